// Round 1
// baseline (206.556 us; speedup 1.0000x reference)
//
#include <hip/hip_runtime.h>
#include <hip/hip_bf16.h>

// ChannelDeAttention: B=64,S=512,C=256,H=128,P=512
// All heavy math in bf16 MFMA (16x16x32), fp32 accum. NT-form GEMMs only.

typedef __attribute__((ext_vector_type(8))) short bf16x8;
typedef __attribute__((ext_vector_type(4))) float f32x4;
typedef __attribute__((ext_vector_type(8))) unsigned short ushort8;

typedef __attribute__((address_space(1))) void* as1vp;
typedef __attribute__((address_space(3))) void* as3vp;

__device__ __forceinline__ void gl2lds16(const void* g, void* l) {
  __builtin_amdgcn_global_load_lds((as1vp)(void*)g, (as3vp)l, 16, 0, 0);
}

__device__ __forceinline__ float bf2f(unsigned short u) {
  union { unsigned int i; float f; } v; v.i = ((unsigned int)u) << 16; return v.f;
}
__device__ __forceinline__ unsigned short f2bf(float f) {
  union { float f; unsigned int i; } v; v.f = f;
  unsigned int r = v.i + 0x7FFFu + ((v.i >> 16) & 1u);
  return (unsigned short)(r >> 16);
}

// ---------------- transpose + fp32->bf16 cast: dst[c][r] = src[r][c] ----------------
// src: [bz][R][Cc] fp32, dst: [bz][Cc][R] bf16. R,Cc multiples of 64.
__global__ void __launch_bounds__(256) tcast(const float* __restrict__ src,
                                             unsigned short* __restrict__ dst,
                                             int R, int Cc) {
  __shared__ float lds[64][65];
  const int t = threadIdx.x;
  const long bz = blockIdx.z;
  const int r0 = blockIdx.x * 64, c0 = blockIdx.y * 64;
  const float* S = src + bz * (long)R * Cc;
  unsigned short* D = dst + bz * (long)R * Cc;
  const int c = t & 63, rbase = (t >> 6) * 16;
#pragma unroll
  for (int i = 0; i < 16; ++i)
    lds[rbase + i][c] = S[(long)(r0 + rbase + i) * Cc + c0 + c];
  __syncthreads();
  const int rr = (t & 31) * 2, ccb = t >> 5;
#pragma unroll
  for (int j = 0; j < 8; ++j) {
    int cc = ccb + j * 8;
    unsigned int u0 = f2bf(lds[rr][cc]);
    unsigned int u1 = f2bf(lds[rr + 1][cc]);
    *(unsigned int*)(D + (long)(c0 + cc) * R + r0 + rr) = u0 | (u1 << 16);
  }
}

// ---------------- generic NT GEMM: C[m][n] = sum_k A[m][k]*B[n][k] (+bias[n]) -------
// 128x128 tile, BK=64, 4 waves (2x2), m97-style global_load_lds staging.
// TRANS: store Out[n][m] (via LDS transpose). F32OUT: fp32 out else bf16.
template <int TRANS, int F32OUT, int BIAS>
__global__ void __launch_bounds__(256) gemm_nt(
    const unsigned short* __restrict__ A, const unsigned short* __restrict__ B,
    void* __restrict__ OutV, const float* __restrict__ bias,
    int lda, int ldb, int K,
    long astr, int asub, int ashift, int amask,
    long bstr, long ostr, int ldo) {
  extern __shared__ char smem[];
  unsigned short* As = (unsigned short*)smem;            // [128][64]
  unsigned short* Bs = (unsigned short*)(smem + 16384);  // [128][64]
  const int t = threadIdx.x;
  const int lane = t & 63, wid = t >> 6;
  const int wm = (wid >> 1) * 64, wn = (wid & 1) * 64;
  const int m0 = blockIdx.y * 128, n0 = blockIdx.x * 128;
  const int bz = blockIdx.z;
  const unsigned short* Ab = A + (long)(bz >> ashift) * astr + (long)(bz & amask) * asub + (long)m0 * lda;
  const unsigned short* Bb = B + (long)bz * bstr + (long)n0 * ldb;
  const int srow = t >> 3, scol = (t & 7) * 8;

  f32x4 acc[4][4] = {};

  for (int k0 = 0; k0 < K; k0 += 64) {
#pragma unroll
    for (int i = 0; i < 4; ++i) {
      gl2lds16(Ab + (long)(i * 32 + srow) * lda + k0 + scol, smem + i * 4096 + t * 16);
      gl2lds16(Bb + (long)(i * 32 + srow) * ldb + k0 + scol, smem + 16384 + i * 4096 + t * 16);
    }
    __syncthreads();
#pragma unroll
    for (int kk = 0; kk < 2; ++kk) {
      bf16x8 af[4], bfr[4];
#pragma unroll
      for (int mi = 0; mi < 4; ++mi)
        af[mi] = *(const bf16x8*)(As + (wm + mi * 16 + (lane & 15)) * 64 + kk * 32 + (lane >> 4) * 8);
#pragma unroll
      for (int ni = 0; ni < 4; ++ni)
        bfr[ni] = *(const bf16x8*)(Bs + (wn + ni * 16 + (lane & 15)) * 64 + kk * 32 + (lane >> 4) * 8);
#pragma unroll
      for (int mi = 0; mi < 4; ++mi)
#pragma unroll
        for (int ni = 0; ni < 4; ++ni)
          acc[mi][ni] = __builtin_amdgcn_mfma_f32_16x16x32_bf16(af[mi], bfr[ni], acc[mi][ni], 0, 0, 0);
    }
    __syncthreads();
  }

  if constexpr (!TRANS) {
    unsigned short* O = (unsigned short*)OutV + (long)bz * ostr;
#pragma unroll
    for (int ni = 0; ni < 4; ++ni) {
      int col = n0 + wn + ni * 16 + (lane & 15);
      float bv_ = BIAS ? bias[col] : 0.0f;
#pragma unroll
      for (int mi = 0; mi < 4; ++mi) {
        int rowb = m0 + wm + mi * 16 + (lane >> 4) * 4;
#pragma unroll
        for (int r = 0; r < 4; ++r)
          O[(long)(rowb + r) * ldo + col] = f2bf(acc[mi][ni][r] + bv_);
      }
    }
  } else {
    // transposed store: Out[n0+n][m0+m], two passes over m-halves via fp32 LDS [64][129]
    float* T = (float*)smem;
    const int LDT = 129;
#pragma unroll
    for (int p = 0; p < 2; ++p) {
      if (wm == p * 64) {
#pragma unroll
        for (int ni = 0; ni < 4; ++ni) {
          int colL = wn + ni * 16 + (lane & 15);
          float bv_ = BIAS ? bias[n0 + colL] : 0.0f;
#pragma unroll
          for (int mi = 0; mi < 4; ++mi)
#pragma unroll
            for (int r = 0; r < 4; ++r)
              T[(mi * 16 + (lane >> 4) * 4 + r) * LDT + colL] = acc[mi][ni][r] + bv_;
        }
      }
      __syncthreads();
      const int mloc = (t & 15) * 4;
#pragma unroll
      for (int j = 0; j < 8; ++j) {
        int n = j * 16 + (t >> 4);
        float v0 = T[(mloc + 0) * LDT + n];
        float v1 = T[(mloc + 1) * LDT + n];
        float v2 = T[(mloc + 2) * LDT + n];
        float v3 = T[(mloc + 3) * LDT + n];
        if constexpr (F32OUT) {
          f32x4 vv = {v0, v1, v2, v3};
          *(f32x4*)((float*)OutV + (long)bz * ostr + (long)(n0 + n) * ldo + m0 + p * 64 + mloc) = vv;
        } else {
          unsigned long long pk = (unsigned long long)f2bf(v0) |
                                  ((unsigned long long)f2bf(v1) << 16) |
                                  ((unsigned long long)f2bf(v2) << 32) |
                                  ((unsigned long long)f2bf(v3) << 48);
          *(unsigned long long*)((unsigned short*)OutV + (long)bz * ostr + (long)(n0 + n) * ldo + m0 + p * 64 + mloc) = pk;
        }
      }
      __syncthreads();
    }
  }
}

// ---------------- scores + row softmax: A = softmax(Q K^T / sqrt(128)) --------------
// Q,K: [bz][256][128] bf16; out: [bz][256][256] bf16. BM=64 (4 waves x 16 rows), N=256.
__global__ void __launch_bounds__(256) scores_sm(const unsigned short* __restrict__ Q,
                                                 const unsigned short* __restrict__ Kt,
                                                 unsigned short* __restrict__ Aout) {
  extern __shared__ char smem[];               // Qs 16K + Ks 32K
  unsigned short* Qs = (unsigned short*)smem;          // [64][128]
  unsigned short* Ks = (unsigned short*)(smem + 16384);// [256][64] chunk
  const int t = threadIdx.x, lane = t & 63, w = t >> 6;
  const long bz = blockIdx.z;
  const int m0 = blockIdx.x * 64;
  const unsigned short* Qb = Q + bz * 32768 + (long)m0 * 128;
  const unsigned short* Kb = Kt + bz * 32768;
  f32x4 acc[16] = {};
  for (int kc = 0; kc < 2; ++kc) {
    if (kc == 0) {
#pragma unroll
      for (int i = 0; i < 4; ++i)
        gl2lds16(Qb + (long)(i * 16 + (t >> 4)) * 128 + (t & 15) * 8, smem + i * 4096 + t * 16);
    }
#pragma unroll
    for (int i = 0; i < 8; ++i)
      gl2lds16(Kb + (long)(i * 32 + (t >> 3)) * 128 + kc * 64 + (t & 7) * 8,
               smem + 16384 + i * 4096 + t * 16);
    __syncthreads();
#pragma unroll
    for (int kk = 0; kk < 2; ++kk) {
      bf16x8 qf = *(const bf16x8*)(Qs + (w * 16 + (lane & 15)) * 128 + kc * 64 + kk * 32 + (lane >> 4) * 8);
#pragma unroll
      for (int ni = 0; ni < 16; ++ni) {
        bf16x8 kf = *(const bf16x8*)(Ks + (ni * 16 + (lane & 15)) * 64 + kk * 32 + (lane >> 4) * 8);
        acc[ni] = __builtin_amdgcn_mfma_f32_16x16x32_bf16(qf, kf, acc[ni], 0, 0, 0);
      }
    }
    __syncthreads();
  }
  const float sc = 0.088388347648318447f;  // 1/sqrt(128)
#pragma unroll
  for (int r = 0; r < 4; ++r) {
    float mx = -1e30f;
#pragma unroll
    for (int ni = 0; ni < 16; ++ni) mx = fmaxf(mx, acc[ni][r]);
#pragma unroll
    for (int off = 1; off < 16; off <<= 1) mx = fmaxf(mx, __shfl_xor(mx, off, 64));
    float s = 0.0f;
#pragma unroll
    for (int ni = 0; ni < 16; ++ni) {
      float p = __expf((acc[ni][r] - mx) * sc);
      acc[ni][r] = p;
      s += p;
    }
#pragma unroll
    for (int off = 1; off < 16; off <<= 1) s += __shfl_xor(s, off, 64);
    float inv = 1.0f / s;
    int row = m0 + w * 16 + (lane >> 4) * 4 + r;
    unsigned short* Orow = Aout + bz * 65536 + (long)row * 256 + (lane & 15);
#pragma unroll
    for (int ni = 0; ni < 16; ++ni) Orow[ni * 16] = f2bf(acc[ni][r] * inv);
  }
}

// ---------------- gate combine: attn = sum_i a_i * softmax_i(a) ---------------------
__global__ void __launch_bounds__(256) gate_combine(const unsigned short* __restrict__ a1,
                                                    const unsigned short* __restrict__ a2,
                                                    const unsigned short* __restrict__ a3,
                                                    unsigned short* __restrict__ attn) {
  long idx = ((long)blockIdx.x * 256 + threadIdx.x) * 8;
  int b = (int)(idx >> 16);
  int r = (int)(idx & 65535);
  const unsigned short* p1 = a1 + ((long)b << 16) + r;
  const unsigned short* p2 = a2 + ((long)(2 * b) << 16) + r;
  const unsigned short* p3 = a3 + ((long)(4 * b) << 16) + r;
  ushort8 v1 = *(const ushort8*)p1;
  ushort8 v2a = *(const ushort8*)p2;
  ushort8 v2b = *(const ushort8*)(p2 + 65536);
  ushort8 v3a = *(const ushort8*)p3;
  ushort8 v3b = *(const ushort8*)(p3 + 65536);
  ushort8 v3c = *(const ushort8*)(p3 + 131072);
  ushort8 v3d = *(const ushort8*)(p3 + 196608);
  ushort8 o;
#pragma unroll
  for (int j = 0; j < 8; ++j) {
    float A1 = bf2f(v1[j]);
    float A2 = 0.5f * (bf2f(v2a[j]) + bf2f(v2b[j]));
    float A3 = 0.25f * (bf2f(v3a[j]) + bf2f(v3b[j]) + bf2f(v3c[j]) + bf2f(v3d[j]));
    float m = fmaxf(A1, fmaxf(A2, A3));
    float e1 = __expf(A1 - m), e2 = __expf(A2 - m), e3 = __expf(A3 - m);
    float out = (A1 * e1 + A2 * e2 + A3 * e3) / (e1 + e2 + e3);
    o[j] = f2bf(out);
  }
  *(ushort8*)(attn + ((long)b << 16) + r) = o;
}

// ------------------------------------------------------------------------------------
extern "C" void kernel_launch(void* const* d_in, const int* in_sizes, int n_in,
                              void* d_out, int out_size, void* d_ws, size_t ws_size,
                              hipStream_t stream) {
  (void)in_sizes; (void)n_in; (void)out_size; (void)ws_size;
  const float* x   = (const float*)d_in[0];
  const float* wq1 = (const float*)d_in[1];
  const float* bq1 = (const float*)d_in[2];
  const float* wk1 = (const float*)d_in[3];
  const float* bk1 = (const float*)d_in[4];
  const float* wq2 = (const float*)d_in[5];
  const float* bq2 = (const float*)d_in[6];
  const float* wk2 = (const float*)d_in[7];
  const float* bk2 = (const float*)d_in[8];
  const float* wq3 = (const float*)d_in[9];
  const float* bq3 = (const float*)d_in[10];
  const float* wk3 = (const float*)d_in[11];
  const float* bk3 = (const float*)d_in[12];
  const float* wv  = (const float*)d_in[13];
  const float* bv  = (const float*)d_in[14];
  const float* wo  = (const float*)d_in[15];
  const float* bo  = (const float*)d_in[16];
  char* ws = (char*)d_ws;

  // workspace layout (bytes); peak ~110.6 MB, aliased regions noted
  const long OFF_XT   = 0;          // [64][256][512] bf16
  const long OFF_WQ1T = 16777216;   // [128][512]
  const long OFF_WK1T = 16908288;
  const long OFF_WQ2T = 17039360;   // [128][256]
  const long OFF_WK2T = 17104896;
  const long OFF_WQ3T = 17170432;   // [128][128]
  const long OFF_WK3T = 17203200;
  const long OFF_WVT  = 17235968;   // [512][512]
  const long OFF_WOT  = 17760256;   // [512][512]
  const long OFF_QB   = 18350080;   // [<=256][256][128] (per-scale reuse)
  const long OFF_KB   = 35127296;
  const long OFF_A1   = 51904512;   // [64][256][256]
  const long OFF_A2   = 60293120;   // [128][256][256]
  const long OFF_A3   = 77070336;   // [256][256][256]  end 110624768
  const long OFF_ATTN = OFF_QB;               // alias (qk dead after scores3)
  const long OFF_VT   = OFF_QB + 8388608;     // alias
  const long OFF_AV   = OFF_A1;               // alias (a1..a3 dead after gate)

  unsigned short* XT   = (unsigned short*)(ws + OFF_XT);
  unsigned short* WQ1T = (unsigned short*)(ws + OFF_WQ1T);
  unsigned short* WK1T = (unsigned short*)(ws + OFF_WK1T);
  unsigned short* WQ2T = (unsigned short*)(ws + OFF_WQ2T);
  unsigned short* WK2T = (unsigned short*)(ws + OFF_WK2T);
  unsigned short* WQ3T = (unsigned short*)(ws + OFF_WQ3T);
  unsigned short* WK3T = (unsigned short*)(ws + OFF_WK3T);
  unsigned short* WVT  = (unsigned short*)(ws + OFF_WVT);
  unsigned short* WOT  = (unsigned short*)(ws + OFF_WOT);
  unsigned short* QB   = (unsigned short*)(ws + OFF_QB);
  unsigned short* KB   = (unsigned short*)(ws + OFF_KB);
  unsigned short* A1P  = (unsigned short*)(ws + OFF_A1);
  unsigned short* A2P  = (unsigned short*)(ws + OFF_A2);
  unsigned short* A3P  = (unsigned short*)(ws + OFF_A3);
  unsigned short* ATTN = (unsigned short*)(ws + OFF_ATTN);
  unsigned short* VT   = (unsigned short*)(ws + OFF_VT);
  unsigned short* AV   = (unsigned short*)(ws + OFF_AV);

  dim3 blk(256);

  // transpose+cast
  tcast<<<dim3(8, 4, 64), blk, 0, stream>>>(x, XT, 512, 256);
  tcast<<<dim3(8, 2, 1), blk, 0, stream>>>(wq1, WQ1T, 512, 128);
  tcast<<<dim3(8, 2, 1), blk, 0, stream>>>(wk1, WK1T, 512, 128);
  tcast<<<dim3(4, 2, 1), blk, 0, stream>>>(wq2, WQ2T, 256, 128);
  tcast<<<dim3(4, 2, 1), blk, 0, stream>>>(wk2, WK2T, 256, 128);
  tcast<<<dim3(2, 2, 1), blk, 0, stream>>>(wq3, WQ3T, 128, 128);
  tcast<<<dim3(2, 2, 1), blk, 0, stream>>>(wk3, WK3T, 128, 128);
  tcast<<<dim3(8, 8, 1), blk, 0, stream>>>(wv, WVT, 512, 512);
  tcast<<<dim3(8, 8, 1), blk, 0, stream>>>(wo, WOT, 512, 512);

  // scale 1: proj q,k -> scores+softmax
  gemm_nt<0, 0, 1><<<dim3(1, 2, 64), blk, 32768, stream>>>(XT, WQ1T, QB, bq1, 512, 512, 512, 131072, 0, 0, 0, 0, 32768, 128);
  gemm_nt<0, 0, 1><<<dim3(1, 2, 64), blk, 32768, stream>>>(XT, WK1T, KB, bk1, 512, 512, 512, 131072, 0, 0, 0, 0, 32768, 128);
  scores_sm<<<dim3(4, 1, 64), blk, 49152, stream>>>(QB, KB, A1P);
  // scale 2
  gemm_nt<0, 0, 1><<<dim3(1, 2, 128), blk, 32768, stream>>>(XT, WQ2T, QB, bq2, 512, 256, 256, 131072, 256, 1, 1, 0, 32768, 128);
  gemm_nt<0, 0, 1><<<dim3(1, 2, 128), blk, 32768, stream>>>(XT, WK2T, KB, bk2, 512, 256, 256, 131072, 256, 1, 1, 0, 32768, 128);
  scores_sm<<<dim3(4, 1, 128), blk, 49152, stream>>>(QB, KB, A2P);
  // scale 3
  gemm_nt<0, 0, 1><<<dim3(1, 2, 256), blk, 32768, stream>>>(XT, WQ3T, QB, bq3, 512, 128, 128, 131072, 128, 2, 3, 0, 32768, 128);
  gemm_nt<0, 0, 1><<<dim3(1, 2, 256), blk, 32768, stream>>>(XT, WK3T, KB, bk3, 512, 128, 128, 131072, 128, 2, 3, 0, 32768, 128);
  scores_sm<<<dim3(4, 1, 256), blk, 49152, stream>>>(QB, KB, A3P);

  // gate combine -> attn
  gate_combine<<<dim3(2048), blk, 0, stream>>>(A1P, A2P, A3P, ATTN);

  // v = x^T wv + bv, stored transposed as vT[s'][c]
  gemm_nt<1, 0, 1><<<dim3(4, 2, 64), blk, 33280, stream>>>(XT, WVT, VT, bv, 512, 512, 512, 131072, 0, 0, 0, 0, 131072, 256);
  // av = attn @ v  (B^T = vT)
  gemm_nt<0, 0, 0><<<dim3(4, 2, 64), blk, 32768, stream>>>(ATTN, VT, AV, nullptr, 256, 256, 256, 65536, 0, 0, 0, 131072, 131072, 512);
  // out[b][p][c] = (av @ wo + bo)^T  (fp32, transposed store)
  gemm_nt<1, 1, 1><<<dim3(4, 2, 64), blk, 33280, stream>>>(AV, WOT, d_out, bo, 512, 512, 512, 131072, 0, 0, 0, 0, 131072, 256);
}

// Round 2
// 155.834 us; speedup vs baseline: 1.3255x; 1.3255x over previous
//
#include <hip/hip_runtime.h>
#include <hip/hip_bf16.h>

// ChannelDeAttention: B=64,S=512,C=256,H=128,P=512
// bf16 MFMA (16x16x32), fp32 accum. 8 launches total.

typedef __attribute__((ext_vector_type(8))) short bf16x8;
typedef __attribute__((ext_vector_type(4))) float f32x4;
typedef __attribute__((ext_vector_type(8))) unsigned short ushort8;

typedef __attribute__((address_space(1))) void* as1vp;
typedef __attribute__((address_space(3))) void* as3vp;

__device__ __forceinline__ void gl2lds16(const void* g, void* l) {
  __builtin_amdgcn_global_load_lds((as1vp)(void*)g, (as3vp)l, 16, 0, 0);
}

__device__ __forceinline__ float bf2f(unsigned short u) {
  union { unsigned int i; float f; } v; v.i = ((unsigned int)u) << 16; return v.f;
}
__device__ __forceinline__ unsigned short f2bf(float f) {
  union { float f; unsigned int i; } v; v.f = f;
  unsigned int r = v.i + 0x7FFFu + ((v.i >> 16) & 1u);
  return (unsigned short)(r >> 16);
}

// ---------------- transpose + fp32->bf16 cast: dst[c][r] = src[r][c] ----------------
__global__ void __launch_bounds__(256) tcast(const float* __restrict__ src,
                                             unsigned short* __restrict__ dst,
                                             int R, int Cc) {
  __shared__ float lds[64][65];
  const int t = threadIdx.x;
  const long bz = blockIdx.z;
  const int r0 = blockIdx.x * 64, c0 = blockIdx.y * 64;
  const float* S = src + bz * (long)R * Cc;
  unsigned short* D = dst + bz * (long)R * Cc;
  const int c = t & 63, rbase = (t >> 6) * 16;
#pragma unroll
  for (int i = 0; i < 16; ++i)
    lds[rbase + i][c] = S[(long)(r0 + rbase + i) * Cc + c0 + c];
  __syncthreads();
  const int rr = (t & 31) * 2, ccb = t >> 5;
#pragma unroll
  for (int j = 0; j < 8; ++j) {
    int cc = ccb + j * 8;
    unsigned int u0 = f2bf(lds[rr][cc]);
    unsigned int u1 = f2bf(lds[rr + 1][cc]);
    *(unsigned int*)(D + (long)(c0 + cc) * R + r0 + rr) = u0 | (u1 << 16);
  }
}

// --------- all weight transposes in one launch (184 tile descriptors) ---------------
// q/k pairs fused: W_s rows 0..127 = wq_s^T, rows 128..255 = wk_s^T (dst ld = fan_in)
__global__ void __launch_bounds__(256) tcast_w(
    const float* __restrict__ wq1, const float* __restrict__ wk1,
    const float* __restrict__ wq2, const float* __restrict__ wk2,
    const float* __restrict__ wq3, const float* __restrict__ wk3,
    const float* __restrict__ wv, const float* __restrict__ wo,
    unsigned short* __restrict__ W1, unsigned short* __restrict__ W2,
    unsigned short* __restrict__ W3, unsigned short* __restrict__ WV,
    unsigned short* __restrict__ WO) {
  __shared__ float lds[64][65];
  const int bid = blockIdx.x;
  const float* S; unsigned short* D; int R, Cc, r0, c0, rowoff = 0;
  if (bid < 32) {
    int m = bid >> 4, i = bid & 15;
    S = m ? wk1 : wq1; D = W1; R = 512; Cc = 128;
    r0 = (i & 7) * 64; c0 = (i >> 3) * 64; rowoff = m * 128;
  } else if (bid < 48) {
    int m = (bid - 32) >> 3, i = (bid - 32) & 7;
    S = m ? wk2 : wq2; D = W2; R = 256; Cc = 128;
    r0 = (i & 3) * 64; c0 = (i >> 2) * 64; rowoff = m * 128;
  } else if (bid < 56) {
    int m = (bid - 48) >> 2, i = (bid - 48) & 3;
    S = m ? wk3 : wq3; D = W3; R = 128; Cc = 128;
    r0 = (i & 1) * 64; c0 = (i >> 1) * 64; rowoff = m * 128;
  } else if (bid < 120) {
    int i = bid - 56; S = wv; D = WV; R = 512; Cc = 512;
    r0 = (i & 7) * 64; c0 = (i >> 3) * 64;
  } else {
    int i = bid - 120; S = wo; D = WO; R = 512; Cc = 512;
    r0 = (i & 7) * 64; c0 = (i >> 3) * 64;
  }
  const int t = threadIdx.x;
  const int c = t & 63, rbase = (t >> 6) * 16;
#pragma unroll
  for (int i = 0; i < 16; ++i)
    lds[rbase + i][c] = S[(long)(r0 + rbase + i) * Cc + c0 + c];
  __syncthreads();
  const int rr = (t & 31) * 2, ccb = t >> 5;
#pragma unroll
  for (int j = 0; j < 8; ++j) {
    int cc = ccb + j * 8;
    unsigned int u0 = f2bf(lds[rr][cc]);
    unsigned int u1 = f2bf(lds[rr + 1][cc]);
    *(unsigned int*)(D + (long)(c0 + cc + rowoff) * R + r0 + rr) = u0 | (u1 << 16);
  }
}

// ---------------- fused Q/K projections, all scales, one launch ---------------------
// grid (2,2,448): z<64 scale1(K=512), z<192 scale2(K=256), else scale3(K=128)
// out QK_s[bz][256][256]: cols 0..127 = q, 128..255 = k
__global__ void __launch_bounds__(256) proj_all(
    const unsigned short* __restrict__ XT,
    const unsigned short* __restrict__ W1, const unsigned short* __restrict__ W2,
    const unsigned short* __restrict__ W3,
    unsigned short* __restrict__ Q1, unsigned short* __restrict__ Q2,
    unsigned short* __restrict__ Q3,
    const float* __restrict__ bq1, const float* __restrict__ bk1,
    const float* __restrict__ bq2, const float* __restrict__ bk2,
    const float* __restrict__ bq3, const float* __restrict__ bk3) {
  extern __shared__ char smem[];
  unsigned short* As = (unsigned short*)smem;            // [128][64]
  unsigned short* Bs = (unsigned short*)(smem + 16384);  // [128][64]
  const int z = blockIdx.z;
  const unsigned short* Ab; const unsigned short* Bw; unsigned short* O;
  const float *bq, *bk; int K;
  if (z < 64) {
    K = 512; Bw = W1; O = Q1 + (long)z * 65536; bq = bq1; bk = bk1;
    Ab = XT + (long)z * 131072;
  } else if (z < 192) {
    int u = z - 64; K = 256; Bw = W2; O = Q2 + (long)u * 65536; bq = bq2; bk = bk2;
    Ab = XT + (long)(u >> 1) * 131072 + (u & 1) * 256;
  } else {
    int u = z - 192; K = 128; Bw = W3; O = Q3 + (long)u * 65536; bq = bq3; bk = bk3;
    Ab = XT + (long)(u >> 2) * 131072 + (u & 3) * 128;
  }
  const int t = threadIdx.x, lane = t & 63, wid = t >> 6;
  const int wm = (wid >> 1) * 64, wn = (wid & 1) * 64;
  const int m0 = blockIdx.y * 128, n0 = blockIdx.x * 128;
  Ab += (long)m0 * 512;
  const unsigned short* Bb = Bw + (long)n0 * K;
  const int srow = t >> 3, scol = (t & 7) * 8;
  f32x4 acc[4][4] = {};
  for (int k0 = 0; k0 < K; k0 += 64) {
#pragma unroll
    for (int i = 0; i < 4; ++i) {
      gl2lds16(Ab + (long)(i * 32 + srow) * 512 + k0 + scol, smem + i * 4096 + t * 16);
      gl2lds16(Bb + (long)(i * 32 + srow) * K + k0 + scol, smem + 16384 + i * 4096 + t * 16);
    }
    __syncthreads();
#pragma unroll
    for (int kk = 0; kk < 2; ++kk) {
      bf16x8 af[4], bfr[4];
#pragma unroll
      for (int mi = 0; mi < 4; ++mi)
        af[mi] = *(const bf16x8*)(As + (wm + mi * 16 + (lane & 15)) * 64 + kk * 32 + (lane >> 4) * 8);
#pragma unroll
      for (int ni = 0; ni < 4; ++ni)
        bfr[ni] = *(const bf16x8*)(Bs + (wn + ni * 16 + (lane & 15)) * 64 + kk * 32 + (lane >> 4) * 8);
#pragma unroll
      for (int mi = 0; mi < 4; ++mi)
#pragma unroll
        for (int ni = 0; ni < 4; ++ni)
          acc[mi][ni] = __builtin_amdgcn_mfma_f32_16x16x32_bf16(af[mi], bfr[ni], acc[mi][ni], 0, 0, 0);
    }
    __syncthreads();
  }
  const float* bias = (n0 == 0) ? bq : bk;
#pragma unroll
  for (int ni = 0; ni < 4; ++ni) {
    int colL = wn + ni * 16 + (lane & 15);
    float bv_ = bias[colL];
#pragma unroll
    for (int mi = 0; mi < 4; ++mi) {
      int rowb = m0 + wm + mi * 16 + (lane >> 4) * 4;
#pragma unroll
      for (int r = 0; r < 4; ++r)
        O[(long)(rowb + r) * 256 + n0 + colL] = f2bf(acc[mi][ni][r] + bv_);
    }
  }
}

// ------------- scores + softmax + sub-batch mean, all scales, one launch ------------
// grid (4,1,192): z<64 scale3(NS=4, heaviest first), z<128 scale2(NS=2), else scale1
__global__ void __launch_bounds__(256) scores_all(
    const unsigned short* __restrict__ QK1, const unsigned short* __restrict__ QK2,
    const unsigned short* __restrict__ QK3,
    unsigned short* __restrict__ A1, unsigned short* __restrict__ A2,
    unsigned short* __restrict__ A3) {
  extern __shared__ char smem[];                // Qs 16K + Ks 32K
  unsigned short* Qs = (unsigned short*)smem;           // [64][128]
  unsigned short* Ks = (unsigned short*)(smem + 16384); // [256][64]
  const int z = blockIdx.z;
  const unsigned short* QK; unsigned short* Aout; int NS, b;
  if (z < 64)       { NS = 4; b = z;       QK = QK3; Aout = A3; }
  else if (z < 128) { NS = 2; b = z - 64;  QK = QK2; Aout = A2; }
  else              { NS = 1; b = z - 128; QK = QK1; Aout = A1; }
  const int t = threadIdx.x, lane = t & 63, w = t >> 6;
  const int m0 = blockIdx.x * 64;
  const float sc = 0.088388347648318447f;  // 1/sqrt(128)
  const float invNS = 1.0f / NS;
  f32x4 avg[16] = {};
  for (int h = 0; h < NS; ++h) {
    const unsigned short* base = QK + ((long)(b * NS + h) << 16);
    f32x4 acc[16] = {};
    for (int kc = 0; kc < 2; ++kc) {
      if (kc == 0) {
#pragma unroll
        for (int i = 0; i < 4; ++i)
          gl2lds16(base + (long)(m0 + i * 16 + (t >> 4)) * 256 + (t & 15) * 8,
                   smem + i * 4096 + t * 16);
      }
#pragma unroll
      for (int i = 0; i < 8; ++i)
        gl2lds16(base + (long)(i * 32 + (t >> 3)) * 256 + 128 + kc * 64 + (t & 7) * 8,
                 smem + 16384 + i * 4096 + t * 16);
      __syncthreads();
#pragma unroll
      for (int kk = 0; kk < 2; ++kk) {
        bf16x8 qf = *(const bf16x8*)(Qs + (w * 16 + (lane & 15)) * 128 + kc * 64 + kk * 32 + (lane >> 4) * 8);
#pragma unroll
        for (int ni = 0; ni < 16; ++ni) {
          bf16x8 kf = *(const bf16x8*)(Ks + (ni * 16 + (lane & 15)) * 64 + kk * 32 + (lane >> 4) * 8);
          acc[ni] = __builtin_amdgcn_mfma_f32_16x16x32_bf16(qf, kf, acc[ni], 0, 0, 0);
        }
      }
      __syncthreads();
    }
#pragma unroll
    for (int r = 0; r < 4; ++r) {
      float mx = -1e30f;
#pragma unroll
      for (int ni = 0; ni < 16; ++ni) mx = fmaxf(mx, acc[ni][r]);
#pragma unroll
      for (int off = 1; off < 16; off <<= 1) mx = fmaxf(mx, __shfl_xor(mx, off, 64));
      float s = 0.0f;
#pragma unroll
      for (int ni = 0; ni < 16; ++ni) {
        float p = __expf((acc[ni][r] - mx) * sc);
        acc[ni][r] = p;
        s += p;
      }
#pragma unroll
      for (int off = 1; off < 16; off <<= 1) s += __shfl_xor(s, off, 64);
      float f = invNS / s;
#pragma unroll
      for (int ni = 0; ni < 16; ++ni) avg[ni][r] += acc[ni][r] * f;
    }
  }
#pragma unroll
  for (int r = 0; r < 4; ++r) {
    int row = m0 + w * 16 + (lane >> 4) * 4 + r;
    unsigned short* Orow = Aout + ((long)b << 16) + (long)row * 256 + (lane & 15);
#pragma unroll
    for (int ni = 0; ni < 16; ++ni) Orow[ni * 16] = f2bf(avg[ni][r]);
  }
}

// ---------------- gate combine: attn = sum_i a_i * softmax_i(a) ---------------------
__global__ void __launch_bounds__(256) gate_combine(const unsigned short* __restrict__ a1,
                                                    const unsigned short* __restrict__ a2,
                                                    const unsigned short* __restrict__ a3,
                                                    unsigned short* __restrict__ attn) {
  long p = ((long)blockIdx.x * 256 + threadIdx.x) * 8;
  ushort8 v1 = *(const ushort8*)(a1 + p);
  ushort8 v2 = *(const ushort8*)(a2 + p);
  ushort8 v3 = *(const ushort8*)(a3 + p);
  ushort8 o;
#pragma unroll
  for (int j = 0; j < 8; ++j) {
    float A1 = bf2f(v1[j]), A2 = bf2f(v2[j]), A3 = bf2f(v3[j]);
    float m = fmaxf(A1, fmaxf(A2, A3));
    float e1 = __expf(A1 - m), e2 = __expf(A2 - m), e3 = __expf(A3 - m);
    float out = (A1 * e1 + A2 * e2 + A3 * e3) / (e1 + e2 + e3);
    o[j] = f2bf(out);
  }
  *(ushort8*)(attn + p) = o;
}

// ---------------- generic NT GEMM (v / av / out) -------------------------------------
template <int TRANS, int F32OUT, int BIAS>
__global__ void __launch_bounds__(256) gemm_nt(
    const unsigned short* __restrict__ A, const unsigned short* __restrict__ B,
    void* __restrict__ OutV, const float* __restrict__ bias,
    int lda, int ldb, int K, long astr, long bstr, long ostr, int ldo) {
  extern __shared__ char smem[];
  unsigned short* As = (unsigned short*)smem;
  unsigned short* Bs = (unsigned short*)(smem + 16384);
  const int t = threadIdx.x;
  const int lane = t & 63, wid = t >> 6;
  const int wm = (wid >> 1) * 64, wn = (wid & 1) * 64;
  const int m0 = blockIdx.y * 128, n0 = blockIdx.x * 128;
  const int bz = blockIdx.z;
  const unsigned short* Ab = A + (long)bz * astr + (long)m0 * lda;
  const unsigned short* Bb = B + (long)bz * bstr + (long)n0 * ldb;
  const int srow = t >> 3, scol = (t & 7) * 8;
  f32x4 acc[4][4] = {};
  for (int k0 = 0; k0 < K; k0 += 64) {
#pragma unroll
    for (int i = 0; i < 4; ++i) {
      gl2lds16(Ab + (long)(i * 32 + srow) * lda + k0 + scol, smem + i * 4096 + t * 16);
      gl2lds16(Bb + (long)(i * 32 + srow) * ldb + k0 + scol, smem + 16384 + i * 4096 + t * 16);
    }
    __syncthreads();
#pragma unroll
    for (int kk = 0; kk < 2; ++kk) {
      bf16x8 af[4], bfr[4];
#pragma unroll
      for (int mi = 0; mi < 4; ++mi)
        af[mi] = *(const bf16x8*)(As + (wm + mi * 16 + (lane & 15)) * 64 + kk * 32 + (lane >> 4) * 8);
#pragma unroll
      for (int ni = 0; ni < 4; ++ni)
        bfr[ni] = *(const bf16x8*)(Bs + (wn + ni * 16 + (lane & 15)) * 64 + kk * 32 + (lane >> 4) * 8);
#pragma unroll
      for (int mi = 0; mi < 4; ++mi)
#pragma unroll
        for (int ni = 0; ni < 4; ++ni)
          acc[mi][ni] = __builtin_amdgcn_mfma_f32_16x16x32_bf16(af[mi], bfr[ni], acc[mi][ni], 0, 0, 0);
    }
    __syncthreads();
  }
  if constexpr (!TRANS) {
    unsigned short* O = (unsigned short*)OutV + (long)bz * ostr;
#pragma unroll
    for (int ni = 0; ni < 4; ++ni) {
      int col = n0 + wn + ni * 16 + (lane & 15);
      float bv_ = BIAS ? bias[col] : 0.0f;
#pragma unroll
      for (int mi = 0; mi < 4; ++mi) {
        int rowb = m0 + wm + mi * 16 + (lane >> 4) * 4;
#pragma unroll
        for (int r = 0; r < 4; ++r)
          O[(long)(rowb + r) * ldo + col] = f2bf(acc[mi][ni][r] + bv_);
      }
    }
  } else {
    float* T = (float*)smem;
    const int LDT = 129;
#pragma unroll
    for (int p = 0; p < 2; ++p) {
      if (wm == p * 64) {
#pragma unroll
        for (int ni = 0; ni < 4; ++ni) {
          int colL = wn + ni * 16 + (lane & 15);
          float bv_ = BIAS ? bias[n0 + colL] : 0.0f;
#pragma unroll
          for (int mi = 0; mi < 4; ++mi)
#pragma unroll
            for (int r = 0; r < 4; ++r)
              T[(mi * 16 + (lane >> 4) * 4 + r) * LDT + colL] = acc[mi][ni][r] + bv_;
        }
      }
      __syncthreads();
      const int mloc = (t & 15) * 4;
#pragma unroll
      for (int j = 0; j < 8; ++j) {
        int n = j * 16 + (t >> 4);
        float v0 = T[(mloc + 0) * LDT + n];
        float v1 = T[(mloc + 1) * LDT + n];
        float v2 = T[(mloc + 2) * LDT + n];
        float v3 = T[(mloc + 3) * LDT + n];
        if constexpr (F32OUT) {
          f32x4 vv = {v0, v1, v2, v3};
          *(f32x4*)((float*)OutV + (long)bz * ostr + (long)(n0 + n) * ldo + m0 + p * 64 + mloc) = vv;
        } else {
          unsigned long long pk = (unsigned long long)f2bf(v0) |
                                  ((unsigned long long)f2bf(v1) << 16) |
                                  ((unsigned long long)f2bf(v2) << 32) |
                                  ((unsigned long long)f2bf(v3) << 48);
          *(unsigned long long*)((unsigned short*)OutV + (long)bz * ostr + (long)(n0 + n) * ldo + m0 + p * 64 + mloc) = pk;
        }
      }
      __syncthreads();
    }
  }
}

// ------------------------------------------------------------------------------------
extern "C" void kernel_launch(void* const* d_in, const int* in_sizes, int n_in,
                              void* d_out, int out_size, void* d_ws, size_t ws_size,
                              hipStream_t stream) {
  (void)in_sizes; (void)n_in; (void)out_size; (void)ws_size;
  const float* x   = (const float*)d_in[0];
  const float* wq1 = (const float*)d_in[1];
  const float* bq1 = (const float*)d_in[2];
  const float* wk1 = (const float*)d_in[3];
  const float* bk1 = (const float*)d_in[4];
  const float* wq2 = (const float*)d_in[5];
  const float* bq2 = (const float*)d_in[6];
  const float* wk2 = (const float*)d_in[7];
  const float* bk2 = (const float*)d_in[8];
  const float* wq3 = (const float*)d_in[9];
  const float* bq3 = (const float*)d_in[10];
  const float* wk3 = (const float*)d_in[11];
  const float* bk3 = (const float*)d_in[12];
  const float* wv  = (const float*)d_in[13];
  const float* bv  = (const float*)d_in[14];
  const float* wo  = (const float*)d_in[15];
  const float* bo  = (const float*)d_in[16];
  char* ws = (char*)d_ws;

  // workspace layout (bytes), peak ~102 MB
  unsigned short* XT   = (unsigned short*)(ws + 0);         // [64][256][512]
  unsigned short* WQK1 = (unsigned short*)(ws + 16777216);  // [256][512]
  unsigned short* WQK2 = (unsigned short*)(ws + 17039360);  // [256][256]
  unsigned short* WQK3 = (unsigned short*)(ws + 17170432);  // [256][128]
  unsigned short* WVT  = (unsigned short*)(ws + 17235968);  // [512][512]
  unsigned short* WOT  = (unsigned short*)(ws + 17760256);  // [512][512]
  unsigned short* QK1  = (unsigned short*)(ws + 18284544);  // [64][256][256]
  unsigned short* QK2  = (unsigned short*)(ws + 26673152);  // [128][256][256]
  unsigned short* QK3  = (unsigned short*)(ws + 43450368);  // [256][256][256]
  unsigned short* A1P  = (unsigned short*)(ws + 77004800);  // [64][256][256]
  unsigned short* A2P  = (unsigned short*)(ws + 85393408);  // [64][256][256]
  unsigned short* A3P  = (unsigned short*)(ws + 93782016);  // [64][256][256]
  unsigned short* ATTN = QK1;  // alias, QK dead after scores_all
  unsigned short* VT   = QK2;  // alias
  unsigned short* AV   = QK3;  // alias

  dim3 blk(256);

  tcast<<<dim3(8, 4, 64), blk, 0, stream>>>(x, XT, 512, 256);
  tcast_w<<<dim3(184), blk, 0, stream>>>(wq1, wk1, wq2, wk2, wq3, wk3, wv, wo,
                                         WQK1, WQK2, WQK3, WVT, WOT);

  proj_all<<<dim3(2, 2, 448), blk, 32768, stream>>>(XT, WQK1, WQK2, WQK3, QK1, QK2, QK3,
                                                    bq1, bk1, bq2, bk2, bq3, bk3);
  scores_all<<<dim3(4, 1, 192), blk, 49152, stream>>>(QK1, QK2, QK3, A1P, A2P, A3P);
  gate_combine<<<dim3(2048), blk, 0, stream>>>(A1P, A2P, A3P, ATTN);

  // v^T = (x^T wv + bv)^T : VT[bz][s'][c]
  gemm_nt<1, 0, 1><<<dim3(4, 2, 64), blk, 33280, stream>>>(
      XT, WVT, VT, bv, 512, 512, 512, 131072, 0, 131072, 256);
  // av = attn @ v (B^T = VT)
  gemm_nt<0, 0, 0><<<dim3(4, 2, 64), blk, 32768, stream>>>(
      ATTN, VT, AV, nullptr, 256, 256, 256, 65536, 131072, 131072, 512);
  // out[b][p][c] = (av @ wo + bo)^T, fp32
  gemm_nt<1, 1, 1><<<dim3(4, 2, 64), blk, 33280, stream>>>(
      AV, WOT, d_out, bo, 512, 512, 512, 131072, 0, 131072, 256);
}

// Round 3
// 146.699 us; speedup vs baseline: 1.4080x; 1.0623x over previous
//
#include <hip/hip_runtime.h>
#include <hip/hip_bf16.h>

// ChannelDeAttention: B=64,S=512,C=256,H=128,P=512
// bf16 MFMA (16x16x32), fp32 accum. 9 launches.

typedef __attribute__((ext_vector_type(8))) short bf16x8;
typedef __attribute__((ext_vector_type(4))) float f32x4;
typedef __attribute__((ext_vector_type(8))) unsigned short ushort8;

typedef __attribute__((address_space(1))) void* as1vp;
typedef __attribute__((address_space(3))) void* as3vp;

__device__ __forceinline__ void gl2lds16(const void* g, void* l) {
  __builtin_amdgcn_global_load_lds((as1vp)(void*)g, (as3vp)l, 16, 0, 0);
}

__device__ __forceinline__ float bf2f(unsigned short u) {
  union { unsigned int i; float f; } v; v.i = ((unsigned int)u) << 16; return v.f;
}
__device__ __forceinline__ unsigned short f2bf(float f) {
  union { float f; unsigned int i; } v; v.f = f;
  unsigned int r = v.i + 0x7FFFu + ((v.i >> 16) & 1u);
  return (unsigned short)(r >> 16);
}

// ---------------- transpose + fp32->bf16 cast: dst[c][r] = src[r][c] ----------------
__global__ void __launch_bounds__(256) tcast(const float* __restrict__ src,
                                             unsigned short* __restrict__ dst,
                                             int R, int Cc) {
  __shared__ float lds[64][65];
  const int t = threadIdx.x;
  const long bz = blockIdx.z;
  const int r0 = blockIdx.x * 64, c0 = blockIdx.y * 64;
  const float* S = src + bz * (long)R * Cc;
  unsigned short* D = dst + bz * (long)R * Cc;
  const int c = t & 63, rbase = (t >> 6) * 16;
#pragma unroll
  for (int i = 0; i < 16; ++i)
    lds[rbase + i][c] = S[(long)(r0 + rbase + i) * Cc + c0 + c];
  __syncthreads();
  const int rr = (t & 31) * 2, ccb = t >> 5;
#pragma unroll
  for (int j = 0; j < 8; ++j) {
    int cc = ccb + j * 8;
    unsigned int u0 = f2bf(lds[rr][cc]);
    unsigned int u1 = f2bf(lds[rr + 1][cc]);
    *(unsigned int*)(D + (long)(c0 + cc) * R + r0 + rr) = u0 | (u1 << 16);
  }
}

// --------- all weight transposes in one launch (184 tile descriptors) ---------------
__global__ void __launch_bounds__(256) tcast_w(
    const float* __restrict__ wq1, const float* __restrict__ wk1,
    const float* __restrict__ wq2, const float* __restrict__ wk2,
    const float* __restrict__ wq3, const float* __restrict__ wk3,
    const float* __restrict__ wv, const float* __restrict__ wo,
    unsigned short* __restrict__ W1, unsigned short* __restrict__ W2,
    unsigned short* __restrict__ W3, unsigned short* __restrict__ WV,
    unsigned short* __restrict__ WO) {
  __shared__ float lds[64][65];
  const int bid = blockIdx.x;
  const float* S; unsigned short* D; int R, Cc, r0, c0, rowoff = 0;
  if (bid < 32) {
    int m = bid >> 4, i = bid & 15;
    S = m ? wk1 : wq1; D = W1; R = 512; Cc = 128;
    r0 = (i & 7) * 64; c0 = (i >> 3) * 64; rowoff = m * 128;
  } else if (bid < 48) {
    int m = (bid - 32) >> 3, i = (bid - 32) & 7;
    S = m ? wk2 : wq2; D = W2; R = 256; Cc = 128;
    r0 = (i & 3) * 64; c0 = (i >> 2) * 64; rowoff = m * 128;
  } else if (bid < 56) {
    int m = (bid - 48) >> 2, i = (bid - 48) & 3;
    S = m ? wk3 : wq3; D = W3; R = 128; Cc = 128;
    r0 = (i & 1) * 64; c0 = (i >> 1) * 64; rowoff = m * 128;
  } else if (bid < 120) {
    int i = bid - 56; S = wv; D = WV; R = 512; Cc = 512;
    r0 = (i & 7) * 64; c0 = (i >> 3) * 64;
  } else {
    int i = bid - 120; S = wo; D = WO; R = 512; Cc = 512;
    r0 = (i & 7) * 64; c0 = (i >> 3) * 64;
  }
  const int t = threadIdx.x;
  const int c = t & 63, rbase = (t >> 6) * 16;
#pragma unroll
  for (int i = 0; i < 16; ++i)
    lds[rbase + i][c] = S[(long)(r0 + rbase + i) * Cc + c0 + c];
  __syncthreads();
  const int rr = (t & 31) * 2, ccb = t >> 5;
#pragma unroll
  for (int j = 0; j < 8; ++j) {
    int cc = ccb + j * 8;
    unsigned int u0 = f2bf(lds[rr][cc]);
    unsigned int u1 = f2bf(lds[rr + 1][cc]);
    *(unsigned int*)(D + (long)(c0 + cc + rowoff) * R + r0 + rr) = u0 | (u1 << 16);
  }
}

// ---------------- fused Q/K projections, all scales, one launch ---------------------
__global__ void __launch_bounds__(256) proj_all(
    const unsigned short* __restrict__ XT,
    const unsigned short* __restrict__ W1, const unsigned short* __restrict__ W2,
    const unsigned short* __restrict__ W3,
    unsigned short* __restrict__ Q1, unsigned short* __restrict__ Q2,
    unsigned short* __restrict__ Q3,
    const float* __restrict__ bq1, const float* __restrict__ bk1,
    const float* __restrict__ bq2, const float* __restrict__ bk2,
    const float* __restrict__ bq3, const float* __restrict__ bk3) {
  extern __shared__ char smem[];
  unsigned short* As = (unsigned short*)smem;            // [128][64]
  unsigned short* Bs = (unsigned short*)(smem + 16384);  // [128][64]
  const int z = blockIdx.z;
  const unsigned short* Ab; const unsigned short* Bw; unsigned short* O;
  const float *bq, *bk; int K;
  if (z < 64) {
    K = 512; Bw = W1; O = Q1 + (long)z * 65536; bq = bq1; bk = bk1;
    Ab = XT + (long)z * 131072;
  } else if (z < 192) {
    int u = z - 64; K = 256; Bw = W2; O = Q2 + (long)u * 65536; bq = bq2; bk = bk2;
    Ab = XT + (long)(u >> 1) * 131072 + (u & 1) * 256;
  } else {
    int u = z - 192; K = 128; Bw = W3; O = Q3 + (long)u * 65536; bq = bq3; bk = bk3;
    Ab = XT + (long)(u >> 2) * 131072 + (u & 3) * 128;
  }
  const int t = threadIdx.x, lane = t & 63, wid = t >> 6;
  const int wm = (wid >> 1) * 64, wn = (wid & 1) * 64;
  const int m0 = blockIdx.y * 128, n0 = blockIdx.x * 128;
  Ab += (long)m0 * 512;
  const unsigned short* Bb = Bw + (long)n0 * K;
  const int srow = t >> 3, scol = (t & 7) * 8;
  f32x4 acc[4][4] = {};
  for (int k0 = 0; k0 < K; k0 += 64) {
#pragma unroll
    for (int i = 0; i < 4; ++i) {
      gl2lds16(Ab + (long)(i * 32 + srow) * 512 + k0 + scol, smem + i * 4096 + t * 16);
      gl2lds16(Bb + (long)(i * 32 + srow) * K + k0 + scol, smem + 16384 + i * 4096 + t * 16);
    }
    __syncthreads();
#pragma unroll
    for (int kk = 0; kk < 2; ++kk) {
      bf16x8 af[4], bfr[4];
#pragma unroll
      for (int mi = 0; mi < 4; ++mi)
        af[mi] = *(const bf16x8*)(As + (wm + mi * 16 + (lane & 15)) * 64 + kk * 32 + (lane >> 4) * 8);
#pragma unroll
      for (int ni = 0; ni < 4; ++ni)
        bfr[ni] = *(const bf16x8*)(Bs + (wn + ni * 16 + (lane & 15)) * 64 + kk * 32 + (lane >> 4) * 8);
#pragma unroll
      for (int mi = 0; mi < 4; ++mi)
#pragma unroll
        for (int ni = 0; ni < 4; ++ni)
          acc[mi][ni] = __builtin_amdgcn_mfma_f32_16x16x32_bf16(af[mi], bfr[ni], acc[mi][ni], 0, 0, 0);
    }
    __syncthreads();
  }
  const float* bias = (n0 == 0) ? bq : bk;
#pragma unroll
  for (int ni = 0; ni < 4; ++ni) {
    int colL = wn + ni * 16 + (lane & 15);
    float bv_ = bias[colL];
#pragma unroll
    for (int mi = 0; mi < 4; ++mi) {
      int rowb = m0 + wm + mi * 16 + (lane >> 4) * 4;
#pragma unroll
      for (int r = 0; r < 4; ++r)
        O[(long)(rowb + r) * 256 + n0 + colL] = f2bf(acc[mi][ni][r] + bv_);
    }
  }
}

// ------------- scores + softmax, uniform blocks, XOR-swizzled LDS -------------------
// block = (sub-batch, 64-row m-tile). grid.x = 4*nsub. sb<split -> (QKa,Aa) else (QKb,Ab).
// LDS swizzle: linear[row][slot] holds global[row][slot^(row&7)] (16B slots, 128B rows);
// achieved by permuting the per-lane GLOBAL source (gl2lds dest must stay linear).
__global__ void __launch_bounds__(256) scores_u(
    const unsigned short* __restrict__ QKa, unsigned short* __restrict__ Aa,
    const unsigned short* __restrict__ QKb, unsigned short* __restrict__ Ab,
    int split) {
  __shared__ unsigned short Qs[64 * 64];    // [64 rows][64 shorts], swizzled
  __shared__ unsigned short Ks[256 * 64];   // [256 rows][64 shorts], swizzled
  const int bid = blockIdx.x;
  const int sb = bid >> 2, m0 = (bid & 3) * 64;
  const unsigned short* QK; unsigned short* Aout;
  if (sb < split) { QK = QKa + (long)sb * 65536; Aout = Aa + (long)sb * 65536; }
  else { int u = sb - split; QK = QKb + (long)u * 65536; Aout = Ab + (long)u * 65536; }
  const int t = threadIdx.x, lane = t & 63, w = t >> 6;
  const int r8 = t >> 3, sl = t & 7;
  f32x4 acc[16] = {};
  for (int kc = 0; kc < 2; ++kc) {
#pragma unroll
    for (int i = 0; i < 2; ++i) {
      int row = i * 32 + r8;
      gl2lds16(QK + (long)(m0 + row) * 256 + kc * 64 + (sl ^ (row & 7)) * 8,
               (char*)Qs + i * 4096 + t * 16);
    }
#pragma unroll
    for (int i = 0; i < 8; ++i) {
      int row = i * 32 + r8;
      gl2lds16(QK + (long)row * 256 + 128 + kc * 64 + (sl ^ (row & 7)) * 8,
               (char*)Ks + i * 4096 + t * 16);
    }
    __syncthreads();
#pragma unroll
    for (int kk = 0; kk < 2; ++kk) {
      const int qrow = w * 16 + (lane & 15);
      const int slot = kk * 4 + (lane >> 4);
      bf16x8 qf = *(const bf16x8*)((char*)Qs + qrow * 128 + 16 * (slot ^ (qrow & 7)));
#pragma unroll
      for (int ni = 0; ni < 16; ++ni) {
        int krow = ni * 16 + (lane & 15);
        bf16x8 kf = *(const bf16x8*)((char*)Ks + krow * 128 + 16 * (slot ^ (krow & 7)));
        acc[ni] = __builtin_amdgcn_mfma_f32_16x16x32_bf16(qf, kf, acc[ni], 0, 0, 0);
      }
    }
    __syncthreads();
  }
  const float sc = 0.088388347648318447f;  // 1/sqrt(128)
#pragma unroll
  for (int r = 0; r < 4; ++r) {
    float mx = -1e30f;
#pragma unroll
    for (int ni = 0; ni < 16; ++ni) mx = fmaxf(mx, acc[ni][r]);
#pragma unroll
    for (int off = 1; off < 16; off <<= 1) mx = fmaxf(mx, __shfl_xor(mx, off, 64));
    float s = 0.0f;
#pragma unroll
    for (int ni = 0; ni < 16; ++ni) {
      float p = __expf((acc[ni][r] - mx) * sc);
      acc[ni][r] = p;
      s += p;
    }
#pragma unroll
    for (int off = 1; off < 16; off <<= 1) s += __shfl_xor(s, off, 64);
    float inv = 1.0f / s;
    int row = m0 + w * 16 + (lane >> 4) * 4 + r;
    unsigned short* Orow = Aout + (long)row * 256 + (lane & 15);
#pragma unroll
    for (int ni = 0; ni < 16; ++ni) Orow[ni * 16] = f2bf(acc[ni][r] * inv);
  }
}

// ------ gate combine with sub-batch mean: attn = sum_i m_i * softmax_i(m) -----------
__global__ void __launch_bounds__(256) gate_combine(const unsigned short* __restrict__ a1,
                                                    const unsigned short* __restrict__ a2,
                                                    const unsigned short* __restrict__ a3,
                                                    unsigned short* __restrict__ attn) {
  long idx = ((long)blockIdx.x * 256 + threadIdx.x) * 8;
  int b = (int)(idx >> 16);
  long r = idx & 65535;
  const unsigned short* p1 = a1 + ((long)b << 16) + r;
  const unsigned short* p2 = a2 + ((long)(2 * b) << 16) + r;
  const unsigned short* p3 = a3 + ((long)(4 * b) << 16) + r;
  ushort8 v1 = *(const ushort8*)p1;
  ushort8 v2a = *(const ushort8*)p2;
  ushort8 v2b = *(const ushort8*)(p2 + 65536);
  ushort8 v3a = *(const ushort8*)p3;
  ushort8 v3b = *(const ushort8*)(p3 + 65536);
  ushort8 v3c = *(const ushort8*)(p3 + 131072);
  ushort8 v3d = *(const ushort8*)(p3 + 196608);
  ushort8 o;
#pragma unroll
  for (int j = 0; j < 8; ++j) {
    float A1 = bf2f(v1[j]);
    float A2 = 0.5f * (bf2f(v2a[j]) + bf2f(v2b[j]));
    float A3 = 0.25f * (bf2f(v3a[j]) + bf2f(v3b[j]) + bf2f(v3c[j]) + bf2f(v3d[j]));
    float m = fmaxf(A1, fmaxf(A2, A3));
    float e1 = __expf(A1 - m), e2 = __expf(A2 - m), e3 = __expf(A3 - m);
    float out = (A1 * e1 + A2 * e2 + A3 * e3) / (e1 + e2 + e3);
    o[j] = f2bf(out);
  }
  *(ushort8*)(attn + ((long)b << 16) + r) = o;
}

// ---------------- generic NT GEMM (v / av / out) -------------------------------------
template <int TRANS, int F32OUT, int BIAS>
__global__ void __launch_bounds__(256) gemm_nt(
    const unsigned short* __restrict__ A, const unsigned short* __restrict__ B,
    void* __restrict__ OutV, const float* __restrict__ bias,
    int lda, int ldb, int K, long astr, long bstr, long ostr, int ldo) {
  extern __shared__ char smem[];
  unsigned short* As = (unsigned short*)smem;
  unsigned short* Bs = (unsigned short*)(smem + 16384);
  const int t = threadIdx.x;
  const int lane = t & 63, wid = t >> 6;
  const int wm = (wid >> 1) * 64, wn = (wid & 1) * 64;
  const int m0 = blockIdx.y * 128, n0 = blockIdx.x * 128;
  const int bz = blockIdx.z;
  const unsigned short* Ab = A + (long)bz * astr + (long)m0 * lda;
  const unsigned short* Bb = B + (long)bz * bstr + (long)n0 * ldb;
  const int srow = t >> 3, scol = (t & 7) * 8;
  f32x4 acc[4][4] = {};
  for (int k0 = 0; k0 < K; k0 += 64) {
#pragma unroll
    for (int i = 0; i < 4; ++i) {
      gl2lds16(Ab + (long)(i * 32 + srow) * lda + k0 + scol, smem + i * 4096 + t * 16);
      gl2lds16(Bb + (long)(i * 32 + srow) * ldb + k0 + scol, smem + 16384 + i * 4096 + t * 16);
    }
    __syncthreads();
#pragma unroll
    for (int kk = 0; kk < 2; ++kk) {
      bf16x8 af[4], bfr[4];
#pragma unroll
      for (int mi = 0; mi < 4; ++mi)
        af[mi] = *(const bf16x8*)(As + (wm + mi * 16 + (lane & 15)) * 64 + kk * 32 + (lane >> 4) * 8);
#pragma unroll
      for (int ni = 0; ni < 4; ++ni)
        bfr[ni] = *(const bf16x8*)(Bs + (wn + ni * 16 + (lane & 15)) * 64 + kk * 32 + (lane >> 4) * 8);
#pragma unroll
      for (int mi = 0; mi < 4; ++mi)
#pragma unroll
        for (int ni = 0; ni < 4; ++ni)
          acc[mi][ni] = __builtin_amdgcn_mfma_f32_16x16x32_bf16(af[mi], bfr[ni], acc[mi][ni], 0, 0, 0);
    }
    __syncthreads();
  }
  if constexpr (!TRANS) {
    unsigned short* O = (unsigned short*)OutV + (long)bz * ostr;
#pragma unroll
    for (int ni = 0; ni < 4; ++ni) {
      int col = n0 + wn + ni * 16 + (lane & 15);
      float bv_ = BIAS ? bias[col] : 0.0f;
#pragma unroll
      for (int mi = 0; mi < 4; ++mi) {
        int rowb = m0 + wm + mi * 16 + (lane >> 4) * 4;
#pragma unroll
        for (int r = 0; r < 4; ++r)
          O[(long)(rowb + r) * ldo + col] = f2bf(acc[mi][ni][r] + bv_);
      }
    }
  } else {
    float* T = (float*)smem;
    const int LDT = 129;
#pragma unroll
    for (int p = 0; p < 2; ++p) {
      if (wm == p * 64) {
#pragma unroll
        for (int ni = 0; ni < 4; ++ni) {
          int colL = wn + ni * 16 + (lane & 15);
          float bv_ = BIAS ? bias[n0 + colL] : 0.0f;
#pragma unroll
          for (int mi = 0; mi < 4; ++mi)
#pragma unroll
            for (int r = 0; r < 4; ++r)
              T[(mi * 16 + (lane >> 4) * 4 + r) * LDT + colL] = acc[mi][ni][r] + bv_;
        }
      }
      __syncthreads();
      const int mloc = (t & 15) * 4;
#pragma unroll
      for (int j = 0; j < 8; ++j) {
        int n = j * 16 + (t >> 4);
        float v0 = T[(mloc + 0) * LDT + n];
        float v1 = T[(mloc + 1) * LDT + n];
        float v2 = T[(mloc + 2) * LDT + n];
        float v3 = T[(mloc + 3) * LDT + n];
        if constexpr (F32OUT) {
          f32x4 vv = {v0, v1, v2, v3};
          *(f32x4*)((float*)OutV + (long)bz * ostr + (long)(n0 + n) * ldo + m0 + p * 64 + mloc) = vv;
        } else {
          unsigned long long pk = (unsigned long long)f2bf(v0) |
                                  ((unsigned long long)f2bf(v1) << 16) |
                                  ((unsigned long long)f2bf(v2) << 32) |
                                  ((unsigned long long)f2bf(v3) << 48);
          *(unsigned long long*)((unsigned short*)OutV + (long)bz * ostr + (long)(n0 + n) * ldo + m0 + p * 64 + mloc) = pk;
        }
      }
      __syncthreads();
    }
  }
}

// ------------------------------------------------------------------------------------
extern "C" void kernel_launch(void* const* d_in, const int* in_sizes, int n_in,
                              void* d_out, int out_size, void* d_ws, size_t ws_size,
                              hipStream_t stream) {
  (void)in_sizes; (void)n_in; (void)out_size; (void)ws_size;
  const float* x   = (const float*)d_in[0];
  const float* wq1 = (const float*)d_in[1];
  const float* bq1 = (const float*)d_in[2];
  const float* wk1 = (const float*)d_in[3];
  const float* bk1 = (const float*)d_in[4];
  const float* wq2 = (const float*)d_in[5];
  const float* bq2 = (const float*)d_in[6];
  const float* wk2 = (const float*)d_in[7];
  const float* bk2 = (const float*)d_in[8];
  const float* wq3 = (const float*)d_in[9];
  const float* bq3 = (const float*)d_in[10];
  const float* wk3 = (const float*)d_in[11];
  const float* bk3 = (const float*)d_in[12];
  const float* wv  = (const float*)d_in[13];
  const float* bv  = (const float*)d_in[14];
  const float* wo  = (const float*)d_in[15];
  const float* bo  = (const float*)d_in[16];
  char* ws = (char*)d_ws;

  // workspace layout (bytes), peak 110,559,232 (within proven 110.6MB budget)
  unsigned short* XT   = (unsigned short*)(ws + 0);         // [64][256][512] 16.8MB
  unsigned short* WQK1 = (unsigned short*)(ws + 16777216);  // [256][512]
  unsigned short* WQK2 = (unsigned short*)(ws + 17039360);  // [256][256]
  unsigned short* WQK3 = (unsigned short*)(ws + 17170432);  // [256][128]
  unsigned short* WVT  = (unsigned short*)(ws + 17235968);  // [512][512]
  unsigned short* WOT  = (unsigned short*)(ws + 17760256);  // [512][512]
  unsigned short* QK1  = (unsigned short*)(ws + 18284544);  // [64][256][256]  8.4MB
  unsigned short* QK2  = (unsigned short*)(ws + 26673152);  // [128][256][256] 16.8MB
  unsigned short* QK3  = (unsigned short*)(ws + 43450368);  // [256][256][256] 33.6MB
  unsigned short* A3P  = (unsigned short*)(ws + 77004800);  // [256][256][256] 33.6MB
  unsigned short* A2P  = (unsigned short*)(ws + 43450368);  // over dead QK3 (after scale3 pass)
  unsigned short* A1P  = (unsigned short*)(ws + 60227584);  // over dead QK3 tail
  unsigned short* ATTN = (unsigned short*)(ws + 18284544);  // over dead QK1 (after gate inputs read)
  unsigned short* VT   = (unsigned short*)(ws + 26673152);  // over dead QK2
  unsigned short* AV   = (unsigned short*)(ws + 77004800);  // over dead A3 (after gate)

  dim3 blk(256);

  tcast<<<dim3(8, 4, 64), blk, 0, stream>>>(x, XT, 512, 256);
  tcast_w<<<dim3(184), blk, 0, stream>>>(wq1, wk1, wq2, wk2, wq3, wk3, wv, wo,
                                         WQK1, WQK2, WQK3, WVT, WOT);

  proj_all<<<dim3(2, 2, 448), blk, 32768, stream>>>(XT, WQK1, WQK2, WQK3, QK1, QK2, QK3,
                                                    bq1, bk1, bq2, bk2, bq3, bk3);

  // scores pass A: scale3 (reads QK3 -> writes A3). pass B: scale2+scale1.
  scores_u<<<dim3(1024), blk, 0, stream>>>(QK3, A3P, QK3, A3P, 256);
  scores_u<<<dim3(768), blk, 0, stream>>>(QK2, A2P, QK1, A1P, 128);

  gate_combine<<<dim3(2048), blk, 0, stream>>>(A1P, A2P, A3P, ATTN);

  // v^T = (x^T wv + bv)^T : VT[bz][s'][c]
  gemm_nt<1, 0, 1><<<dim3(4, 2, 64), blk, 33280, stream>>>(
      XT, WVT, VT, bv, 512, 512, 512, 131072, 0, 131072, 256);
  // av = attn @ v (B^T = VT)
  gemm_nt<0, 0, 0><<<dim3(4, 2, 64), blk, 32768, stream>>>(
      ATTN, VT, AV, nullptr, 256, 256, 256, 65536, 131072, 131072, 512);
  // out[b][p][c] = (av @ wo + bo)^T, fp32
  gemm_nt<1, 1, 1><<<dim3(4, 2, 64), blk, 33280, stream>>>(
      AV, WOT, d_out, bo, 512, 512, 512, 131072, 0, 131072, 256);
}